// Round 13
// baseline (193.089 us; speedup 1.0000x reference)
//
#include <hip/hip_runtime.h>
#include <stdint.h>

// MultiHeadAttention: S=2048 B=2 D=1024 H=16 HD=64 — fp32 in/out.
// Round 18 == Round 17 resubmit (infra failure; QB=64 still unmeasured).
//   R16 post-mortem: GEMM BK=64 gave +4% not +30% — R13(32it x 3.3K) vs
//   R14(16it x 6.6K) = identical total cycles -> cost scales with WORK not
//   iteration count; barrier-overhead model falsified. GEMM frozen at 43.9us.
//   attn (41.1us): Occ 15.7% (grid 2 blocks/CU; LDS would allow 3),
//   latency-bound. Fix: QB 128->64 (1 Q-tile/wave), LDS 42KB, grid 1024
//   -> 3 blocks/CU (12 waves). Also hoist masked-tail select (wave-uniform
//   tail flag) out of full tiles. Sync structure identical to verified v7.

#define S_ 2048
#define B_ 2
#define D_ 1024
#define H_ 16
#define HD_ 64
#define M_ (S_ * B_)

typedef __bf16 bf16;
typedef bf16 bf16x8 __attribute__((ext_vector_type(8)));
typedef float floatx4 __attribute__((ext_vector_type(4)));

#define QSCALE 0.18033688011112042f   // (1/sqrt(64)) * log2(e)

#if __has_builtin(__builtin_amdgcn_exp2f)
#define EXP2F(x) __builtin_amdgcn_exp2f(x)
#else
#define EXP2F(x) exp2f(x)
#endif

__device__ __forceinline__ void async_cp16(const bf16* g, bf16* l) {
    __builtin_amdgcn_global_load_lds(
        (const __attribute__((address_space(1))) void*)g,
        (__attribute__((address_space(3))) void*)l, 16, 0, 0);
}

// ---------------------------------------------------------------------------
// mask scan: cnt = #unmasked, sidx[p] = p-th unmasked s (ascending)
// ---------------------------------------------------------------------------
__global__ __launch_bounds__(256) void mask_scan(const int* __restrict__ mask,
                                                 int* __restrict__ sidx,
                                                 int* __restrict__ cnt)
{
    __shared__ int sums[256];
    const int tid = threadIdx.x;
    int v[8], s = 0;
    #pragma unroll
    for (int j = 0; j < 8; j++) { v[j] = mask[tid * 8 + j] ? 1 : 0; s += v[j]; }
    sums[tid] = s;
    __syncthreads();
    for (int off = 1; off < 256; off <<= 1) {
        int t = (tid >= off) ? sums[tid - off] : 0;
        __syncthreads();
        sums[tid] += t;
        __syncthreads();
    }
    int base = (tid > 0) ? sums[tid - 1] : 0;
    #pragma unroll
    for (int j = 0; j < 8; j++)
        if (v[j]) { sidx[base] = tid * 8 + j; base++; }
    if (tid == 255) cnt[0] = sums[255];
}

// ---------------------------------------------------------------------------
// X convert (+gather for K/V): z=0 straight; z=1,2 compacted by sidx.
// ---------------------------------------------------------------------------
__global__ __launch_bounds__(256) void cvt_gather(
    const float* __restrict__ xq, const float* __restrict__ xk, const float* __restrict__ xv,
    const int* __restrict__ sidx, const int* __restrict__ cnt,
    bf16* __restrict__ oq, bf16* __restrict__ ok, bf16* __restrict__ ov)
{
    const int z = blockIdx.y;
    const float* src = (z == 0) ? xq : (z == 1) ? xk : xv;
    bf16*        dst = (z == 0) ? oq : (z == 1) ? ok : ov;

    const int tid = threadIdx.x;
    const int rm  = blockIdx.x * 2 + (tid >> 7);   // dest row
    int srow = rm;
    if (z != 0) {
        const int cs = rm >> 1, b = rm & 1;
        if (cs >= cnt[0]) return;                  // uniform per block
        srow = sidx[cs] * 2 + b;
    }
    const int col = (tid & 127) * 8;
    const floatx4* sp = (const floatx4*)(src + (size_t)srow * D_ + col);
    floatx4 x0 = sp[0], x1 = sp[1];
    bf16x8 v;
    #pragma unroll
    for (int j = 0; j < 4; j++) { v[j] = (bf16)x0[j]; v[4 + j] = (bf16)x1[j]; }
    *(bf16x8*)(dst + (size_t)rm * D_ + col) = v;
}

// ---------------------------------------------------------------------------
// W fp32 -> bf16
// ---------------------------------------------------------------------------
__global__ __launch_bounds__(256) void cvt3(
    const float* __restrict__ a, const float* __restrict__ b, const float* __restrict__ c,
    bf16* __restrict__ oa, bf16* __restrict__ ob, bf16* __restrict__ oc)
{
    const int z = blockIdx.z;
    const float* src = (z == 0) ? a : (z == 1) ? b : c;
    bf16*        dst = (z == 0) ? oa : (z == 1) ? ob : oc;
    const size_t i = ((size_t)blockIdx.x * 256 + threadIdx.x) * 8;
    floatx4 x0 = *(const floatx4*)(src + i);
    floatx4 x1 = *(const floatx4*)(src + i + 4);
    bf16x8 v;
    #pragma unroll
    for (int j = 0; j < 4; j++) { v[j] = (bf16)x0[j]; v[4 + j] = (bf16)x1[j]; }
    *(bf16x8*)(dst + i) = v;
}

#define TM 128
#define TN 128
#define BK 64

// ---------------------------------------------------------------------------
// Fused QKV GEMM v4 (verified R16): counted-vmcnt 2-deep pipeline, BK=64,
// raw s_barrier, explicit waits, both-sides chunk swizzle.
//   z=0: Q[bh][s][hd]   = (X_q W_q^T + b_q) * QSCALE      (full 4096 rows)
//   z=1: K[bh][cs][hd]  =  X_kc W_k^T + b_k               (2*cnt rows)
//   z=2: VT[bh][hd][cs] =  X_vc W_v^T + b_v, via operand swap (2*cnt rows)
// ---------------------------------------------------------------------------
__global__ __launch_bounds__(256) void qkv_gemm_async(
    const bf16* __restrict__ xq, const bf16* __restrict__ xk, const bf16* __restrict__ xv,
    const bf16* __restrict__ wq, const bf16* __restrict__ wk, const bf16* __restrict__ wv,
    const float* __restrict__ bq, const float* __restrict__ bk, const float* __restrict__ bv,
    const int* __restrict__ cnt,
    bf16* __restrict__ oq, bf16* __restrict__ ok, bf16* __restrict__ ov)
{
    __shared__ __align__(16) bf16 a_lds[2][TM * BK];   // X tiles, 2 x 16 KB
    __shared__ __align__(16) bf16 b_lds[2][TN * BK];   // W tiles, 2 x 16 KB

    const int z = blockIdx.y;
    const bf16*  X  = (z == 0) ? xq : (z == 1) ? xk : xv;
    const bf16*  W  = (z == 0) ? wq : (z == 1) ? wk : wv;
    const float* Bi = (z == 0) ? bq : (z == 1) ? bk : bv;
    bf16*        O  = (z == 0) ? oq : (z == 1) ? ok : ov;

    // XCD swizzle: id%8 -> XCD (round-robin). XCD k gets mb in {k,8+k,16+k,24+k}
    const int f   = blockIdx.x;
    const int xcd = f & 7, t = f >> 3;
    const int m0  = ((t & 3) * 8 + xcd) * TM;
    const int n0  = (t >> 2) * TN;

    const int rows_active = (z == 0) ? M_ : 2 * cnt[0];
    if (m0 >= rows_active) return;

    const int tid  = threadIdx.x;
    const int wid  = tid >> 6;
    const int lane = tid & 63;
    const int wm = wid >> 1, wn = wid & 1;
    const int lm = lane & 15, lq = lane >> 4;

    // z==2: swap A/B so MFMA emits V^T (C-row = W-row = d, C-col = X-row = key)
    const int a_base = ((z == 2) ? wn : wm) * 64;
    const int b_base = ((z == 2) ? wm : wn) * 64;

    // staging precompute: 1024 chunks/tile/matrix, 4 per thread per matrix.
    // chunk c -> row=c>>3, swizzled k-chunk kcs=(c&7)^((c>>3)&7)
    const bf16* xs[4];
    const bf16* ws[4];
    int la[4];
    #pragma unroll
    for (int q = 0; q < 4; q++) {
        const int c   = (q * 4 + wid) * 64 + lane;
        const int row = c >> 3;
        const int kcs = ((c & 7) ^ (row & 7)) * 8;
        xs[q] = X + (size_t)(m0 + row) * D_ + kcs;
        ws[q] = W + (size_t)(n0 + row) * D_ + kcs;
        la[q] = (q * 4 + wid) * 512;   // wave-uniform LDS elem offset (64 ch x 8)
    }

    #define GEMM_STAGE(buf, kt)                                   \
        {                                                         \
            _Pragma("unroll")                                     \
            for (int q = 0; q < 4; q++) {                         \
                async_cp16(xs[q] + (kt), &a_lds[buf][la[q]]);     \
                async_cp16(ws[q] + (kt), &b_lds[buf][la[q]]);     \
            }                                                     \
        }

    floatx4 acc[4][4] = {};

    // prologue: 2 tiles in flight (16 loads/thread)
    GEMM_STAGE(0, 0);
    GEMM_STAGE(1, BK);

    const int nk = D_ / BK;   // 16
    for (int ki = 0; ki < nk; ki++) {
        const int cur = ki & 1;

        // own tile-ki loads landed (tile ki+1's 8 loads stay in flight)
        if (ki + 1 < nk) asm volatile("s_waitcnt vmcnt(8)" ::: "memory");
        else             asm volatile("s_waitcnt vmcnt(0)" ::: "memory");
        __builtin_amdgcn_sched_barrier(0);
        __builtin_amdgcn_s_barrier();          // tile-ki landed block-wide
        __builtin_amdgcn_sched_barrier(0);

        const bf16* src_a = (z == 2) ? b_lds[cur] : a_lds[cur];
        const bf16* src_b = (z == 2) ? a_lds[cur] : b_lds[cur];

        // all 16 fragments of buf[cur] -> regs (must complete before barrier 2)
        bf16x8 af[4][2], bfv[4][2];
        #pragma unroll
        for (int i = 0; i < 4; i++) {
            const int r = a_base + i * 16 + lm;
            #pragma unroll
            for (int ks = 0; ks < 2; ks++)
                af[i][ks] = *(const bf16x8*)(src_a + r * BK +
                                (((ks * 4 + lq) ^ (r & 7)) * 8));
        }
        #pragma unroll
        for (int j = 0; j < 4; j++) {
            const int r = b_base + j * 16 + lm;
            #pragma unroll
            for (int ks = 0; ks < 2; ks++)
                bfv[j][ks] = *(const bf16x8*)(src_b + r * BK +
                                (((ks * 4 + lq) ^ (r & 7)) * 8));
        }
        asm volatile("s_waitcnt lgkmcnt(0)" ::: "memory");   // reads in regs
        __builtin_amdgcn_sched_barrier(0);                   // rule #18 fence
        __builtin_amdgcn_s_barrier();          // all reads of buf[cur] done
        __builtin_amdgcn_sched_barrier(0);

        // refill the just-freed buffer (issue before MFMA for overlap)
        if (ki + 2 < nk) GEMM_STAGE(cur, (ki + 2) * BK);

        __builtin_amdgcn_s_setprio(1);
        #pragma unroll
        for (int ks = 0; ks < 2; ks++)
            #pragma unroll
            for (int i = 0; i < 4; i++)
                #pragma unroll
                for (int j = 0; j < 4; j++)
                    acc[i][j] = __builtin_amdgcn_mfma_f32_16x16x32_bf16(
                        af[i][ks], bfv[j][ks], acc[i][j], 0, 0, 0);
        __builtin_amdgcn_s_setprio(0);
    }
    #undef GEMM_STAGE

    // C/D layout: col = lane&15 (B-side), row = lq*4 + reg (A-side).
    if (z != 2) {
        #pragma unroll
        for (int j = 0; j < 4; j++) {
            const int n = n0 + wn * 64 + j * 16 + lm;          // W row
            const float bias = Bi[n];
            const int h = n >> 6, hd = n & 63;
            #pragma unroll
            for (int i = 0; i < 4; i++) {
                const int mb = m0 + wm * 64 + i * 16 + lq * 4;
                #pragma unroll
                for (int r = 0; r < 4; r++) {
                    const int m = mb + r;                      // X row
                    const int row = m >> 1, b = m & 1;         // s or cs
                    float v = acc[i][j][r] + bias;
                    if (z == 0) v *= QSCALE;
                    O[(((size_t)(b * H_ + h)) * S_ + row) * HD_ + hd] = (bf16)v;
                }
            }
        }
    } else {
        #pragma unroll
        for (int j = 0; j < 4; j++) {
            const int m = m0 + wm * 64 + j * 16 + lm;          // X row (key)
            const int cs = m >> 1, b = m & 1;
            #pragma unroll
            for (int i = 0; i < 4; i++) {
                const int wb = n0 + wn * 64 + i * 16 + lq * 4;
                #pragma unroll
                for (int r = 0; r < 4; r++) {
                    const int n = wb + r;                      // W row
                    const float bias = Bi[n];
                    const int h = n >> 6, d = n & 63;
                    O[(((size_t)(b * H_ + h)) * HD_ + d) * S_ + cs] =
                        (bf16)(acc[i][j][r] + bias);
                }
            }
        }
    }
}

// ---------------------------------------------------------------------------
// MFMA flash attention over cnt compacted keys. K[bh][cs][d], VT[bh][d][cs].
// v8: QB=64 (1 Q-tile/wave) -> LDS 42KB, 1024 blocks, 3 blocks/CU.
// Masked-tail select hoisted behind wave-uniform `tail` flag.
// Sync structure identical to verified v7 (dbuf K/V, async-stage,
// 1 barrier/KV-tile, wave-local lgkmcnt for P, setprio, native exp2,
// XCD bh-affinity).
// ---------------------------------------------------------------------------
#define KT 64
#define QB 64

__global__ __launch_bounds__(256) void attn_kernel(
    const bf16* __restrict__ qw, const bf16* __restrict__ kw, const bf16* __restrict__ vtw,
    const int* __restrict__ cnt, float* __restrict__ out)
{
    __shared__ __align__(16) bf16 k_lds[2 * KT * HD_];      // [buf][kj][d], 16 KB
    __shared__ __align__(16) bf16 v_ldsT[2 * HD_ * KT];     // [buf][d][kj], 16 KB
    __shared__ __align__(16) bf16 p_lds[4 * 16 * 72];       // [wave][row][72], 9 KB

    const int tid  = threadIdx.x;
    const int wid  = tid >> 6;
    const int lane = tid & 63;
    const int lm = lane & 15, lq = lane >> 4;

    // XCD bh-affinity: id%8 -> XCD; XCD x owns bh in {4x..4x+3};
    // 32 q-blocks per bh -> K/V L2-resident per XCD.
    const int id  = blockIdx.x;
    const int j   = id >> 3;
    const int bh  = (id & 7) * 4 + (j >> 5);
    const int q0  = (j & 31) * QB;
    const int count = cnt[0];

    const bf16* Qb  = qw  + (size_t)bh * S_ * HD_;
    const bf16* Kb  = kw  + (size_t)bh * S_ * HD_;
    const bf16* VTb = vtw + (size_t)bh * HD_ * S_;

    // Q fragments: one 16-row tile per wave (rows q0 + wid*16 + lm)
    bf16x8 qf[2];
    {
        const bf16* qp = Qb + (size_t)(q0 + wid * 16 + lm) * HD_;
        qf[0] = *(const bf16x8*)(qp + lq * 8);
        qf[1] = *(const bf16x8*)(qp + 32 + lq * 8);
    }

    float lsum[4] = {};
    floatx4 oacc[4] = {};
    bf16* pwb = p_lds + wid * (16 * 72);

    // staging geometry: 512 16B-chunks per 64x64 tile, 2 per thread
    const int c0row = tid >> 3, c0ch = tid & 7;          // chunk tid
    const int c1row = (tid + 256) >> 3, c1ch = tid & 7;  // chunk tid+256

    // prologue: stage tile 0 into buf 0
    {
        bf16x8 kv0 = *(const bf16x8*)(Kb + (size_t)c0row * HD_ + c0ch * 8);
        bf16x8 kv1 = *(const bf16x8*)(Kb + (size_t)c1row * HD_ + c1ch * 8);
        bf16x8 vv0 = *(const bf16x8*)(VTb + (size_t)c0row * S_ + c0ch * 8);
        bf16x8 vv1 = *(const bf16x8*)(VTb + (size_t)c1row * S_ + c1ch * 8);
        *(bf16x8*)(k_lds + c0row * 64 + ((c0ch ^ (c0row & 7)) * 8)) = kv0;
        *(bf16x8*)(k_lds + c1row * 64 + ((c1ch ^ (c1row & 7)) * 8)) = kv1;
        *(bf16x8*)(v_ldsT + c0row * 64 + ((c0ch ^ (c0row & 7)) * 8)) = vv0;
        *(bf16x8*)(v_ldsT + c1row * 64 + ((c1ch ^ (c1row & 7)) * 8)) = vv1;
    }
    __syncthreads();

    const int nt = (count + KT - 1) / KT;
    for (int it = 0; it < nt; ++it) {
        const int j0  = it * KT;
        const int cur = it & 1, nxt = cur ^ 1;
        const bool has_next = (it + 1 < nt);
        const bool tail = (j0 + KT > count);       // wave-uniform
        const bf16* kc = k_lds + cur * (KT * 64);
        const bf16* vc = v_ldsT + cur * (KT * 64);

        // T14 async-STAGE: issue next tile's global loads now, LDS-write after PV
        bf16x8 kreg0, kreg1, vreg0, vreg1;
        if (has_next) {
            const int jn = j0 + KT;
            kreg0 = *(const bf16x8*)(Kb + (size_t)(jn + c0row) * HD_ + c0ch * 8);
            kreg1 = *(const bf16x8*)(Kb + (size_t)(jn + c1row) * HD_ + c1ch * 8);
            vreg0 = *(const bf16x8*)(VTb + (size_t)c0row * S_ + jn + c0ch * 8);
            vreg1 = *(const bf16x8*)(VTb + (size_t)c1row * S_ + jn + c1ch * 8);
        }

        // QK^T
        floatx4 sacc[4] = {};
        __builtin_amdgcn_s_setprio(1);
        #pragma unroll
        for (int ks = 0; ks < 2; ks++)
            #pragma unroll
            for (int n = 0; n < 4; n++) {
                bf16x8 kf = *(const bf16x8*)(kc + (n * 16 + lm) * 64 +
                                             (((ks * 4 + lq) ^ (lm & 7)) * 8));
                sacc[n] = __builtin_amdgcn_mfma_f32_16x16x32_bf16(qf[ks], kf, sacc[n], 0, 0, 0);
            }
        __builtin_amdgcn_s_setprio(0);

        // p = exp2(score) via native v_exp_f32. Tail tile only: select
        // (not multiply) past count so garbage K rows can't poison lsum.
        if (!tail) {
            #pragma unroll
            for (int r = 0; r < 4; r++)
                #pragma unroll
                for (int n = 0; n < 4; n++) {
                    const float p = EXP2F(sacc[n][r]);
                    lsum[r] += p;
                    pwb[(lq * 4 + r) * 72 + n * 16 + lm] = (bf16)p;
                }
        } else {
            bool valid[4];
            #pragma unroll
            for (int n = 0; n < 4; n++)
                valid[n] = (j0 + n * 16 + lm < count);
            #pragma unroll
            for (int r = 0; r < 4; r++)
                #pragma unroll
                for (int n = 0; n < 4; n++) {
                    const float p = valid[n] ? EXP2F(sacc[n][r]) : 0.0f;
                    lsum[r] += p;
                    pwb[(lq * 4 + r) * 72 + n * 16 + lm] = (bf16)p;
                }
        }

        // p_lds is per-wave: wave-local drain is enough (no block barrier).
        asm volatile("s_waitcnt lgkmcnt(0)" ::: "memory");
        __builtin_amdgcn_sched_barrier(0);

        // PV (A = P, B = V^T rows)
        __builtin_amdgcn_s_setprio(1);
        #pragma unroll
        for (int ks = 0; ks < 2; ks++) {
            bf16x8 pf = *(const bf16x8*)(pwb + lm * 72 + ks * 32 + lq * 8);
            #pragma unroll
            for (int n = 0; n < 4; n++) {
                bf16x8 vf = *(const bf16x8*)(vc + (n * 16 + lm) * 64 +
                                             (((ks * 4 + lq) ^ (lm & 7)) * 8));
                oacc[n] = __builtin_amdgcn_mfma_f32_16x16x32_bf16(pf, vf, oacc[n], 0, 0, 0);
            }
        }
        __builtin_amdgcn_s_setprio(0);

        // write staged regs into the other buffer (nobody reads it: barrier at
        // end of prev iter guaranteed all reads of buf[nxt] completed)
        if (has_next) {
            bf16* kd = k_lds + nxt * (KT * 64);
            bf16* vd = v_ldsT + nxt * (KT * 64);
            *(bf16x8*)(kd + c0row * 64 + ((c0ch ^ (c0row & 7)) * 8)) = kreg0;
            *(bf16x8*)(kd + c1row * 64 + ((c1ch ^ (c1row & 7)) * 8)) = kreg1;
            *(bf16x8*)(vd + c0row * 64 + ((c0ch ^ (c0row & 7)) * 8)) = vreg0;
            *(bf16x8*)(vd + c1row * 64 + ((c1ch ^ (c1row & 7)) * 8)) = vreg1;
        }
        __syncthreads();   // one barrier per KV-tile
    }

    float invl[4];
    #pragma unroll
    for (int r = 0; r < 4; r++) {
        float lr = lsum[r];
        lr += __shfl_xor(lr, 1);
        lr += __shfl_xor(lr, 2);
        lr += __shfl_xor(lr, 4);
        lr += __shfl_xor(lr, 8);
        invl[r] = 1.0f / lr;
    }
    const int b = bh >> 4, h = bh & 15;
    #pragma unroll
    for (int n = 0; n < 4; n++)
        #pragma unroll
        for (int r = 0; r < 4; r++) {
            const int q = q0 + wid * 16 + lq * 4 + r;
            out[((size_t)q * B_ + b) * D_ + h * 64 + n * 16 + lm] =
                oacc[n][r] * invl[r];
        }
}

// ---------------------------------------------------------------------------
extern "C" void kernel_launch(void* const* d_in, const int* in_sizes, int n_in,
                              void* d_out, int out_size, void* d_ws, size_t ws_size,
                              hipStream_t stream) {
    const float* xq = (const float*)d_in[0];
    const float* xk = (const float*)d_in[1];
    const float* xv = (const float*)d_in[2];
    const int*  mask = (const int*)d_in[3];
    const float* wq = (const float*)d_in[4];
    const float* bq = (const float*)d_in[5];
    const float* wk = (const float*)d_in[6];
    const float* bk = (const float*)d_in[7];
    const float* wv = (const float*)d_in[8];
    const float* bv = (const float*)d_in[9];

    const size_t NX = (size_t)M_ * D_;      // 4194304
    const size_t NW = (size_t)D_ * D_;      // 1048576
    char* ws = (char*)d_ws;
    int* cnt  = (int*)ws;
    int* sidx = cnt + 16;
    char* base = ws + 16384;

    bf16* xqb = (bf16*)base;
    bf16* xkb = xqb + NX;
    bf16* xvb = xkb + NX;
    bf16* wqb = xvb + NX;
    bf16* wkb = wqb + NW;
    bf16* wvb = wkb + NW;
    bf16* q_ws  = wvb + NW;
    bf16* k_ws  = q_ws + NX;
    bf16* vt_ws = k_ws + NX;

    mask_scan<<<1, 256, 0, stream>>>(mask, sidx, cnt);
    cvt_gather<<<dim3(M_ / 2, 3), 256, 0, stream>>>(xq, xk, xv, sidx, cnt,
                                                    xqb, xkb, xvb);
    cvt3<<<dim3(NW / 2048, 1, 3), 256, 0, stream>>>(wq, wk, wv, wqb, wkb, wvb);

    qkv_gemm_async<<<dim3(256, 3), 256, 0, stream>>>(xqb, xkb, xvb, wqb, wkb, wvb,
                                                     bq, bk, bv, cnt,
                                                     q_ws, k_ws, vt_ws);

    attn_kernel<<<dim3((S_ / QB) * B_ * H_), 256, 0, stream>>>(q_ws, k_ws, vt_ws,
                                                               cnt, (float*)d_out);
}

// Round 14
// 180.017 us; speedup vs baseline: 1.0726x; 1.0726x over previous
//
#include <hip/hip_runtime.h>
#include <stdint.h>

// MultiHeadAttention: S=2048 B=2 D=1024 H=16 HD=64 — fp32 in/out.
// Round 19: REVERT attn to verified v7 (QB=128). R17 post-mortem: QB=64
//   regressed 41.1->50.0us — staging work per block is QB-independent, so
//   halving QB doubled staging traffic/barriers per Q-row; amortization
//   dominates occupancy for this kernel. v7 restored + sync-neutral
//   tail-hoist only (wave-uniform flag skips masked-select on full tiles).
//   - qkv_gemm_async v4 (verified R16): counted-vmcnt 2-deep, BK=64.
//   - attn v7.1: QB=128, 2 Q-tiles/wave, dbuf K/V, async-stage, 1 barrier,
//     native exp2, XCD bh-affinity, tail-hoisted masked select.

#define S_ 2048
#define B_ 2
#define D_ 1024
#define H_ 16
#define HD_ 64
#define M_ (S_ * B_)

typedef __bf16 bf16;
typedef bf16 bf16x8 __attribute__((ext_vector_type(8)));
typedef float floatx4 __attribute__((ext_vector_type(4)));

#define QSCALE 0.18033688011112042f   // (1/sqrt(64)) * log2(e)

#if __has_builtin(__builtin_amdgcn_exp2f)
#define EXP2F(x) __builtin_amdgcn_exp2f(x)
#else
#define EXP2F(x) exp2f(x)
#endif

__device__ __forceinline__ void async_cp16(const bf16* g, bf16* l) {
    __builtin_amdgcn_global_load_lds(
        (const __attribute__((address_space(1))) void*)g,
        (__attribute__((address_space(3))) void*)l, 16, 0, 0);
}

// ---------------------------------------------------------------------------
// mask scan: cnt = #unmasked, sidx[p] = p-th unmasked s (ascending)
// ---------------------------------------------------------------------------
__global__ __launch_bounds__(256) void mask_scan(const int* __restrict__ mask,
                                                 int* __restrict__ sidx,
                                                 int* __restrict__ cnt)
{
    __shared__ int sums[256];
    const int tid = threadIdx.x;
    int v[8], s = 0;
    #pragma unroll
    for (int j = 0; j < 8; j++) { v[j] = mask[tid * 8 + j] ? 1 : 0; s += v[j]; }
    sums[tid] = s;
    __syncthreads();
    for (int off = 1; off < 256; off <<= 1) {
        int t = (tid >= off) ? sums[tid - off] : 0;
        __syncthreads();
        sums[tid] += t;
        __syncthreads();
    }
    int base = (tid > 0) ? sums[tid - 1] : 0;
    #pragma unroll
    for (int j = 0; j < 8; j++)
        if (v[j]) { sidx[base] = tid * 8 + j; base++; }
    if (tid == 255) cnt[0] = sums[255];
}

// ---------------------------------------------------------------------------
// X convert (+gather for K/V): z=0 straight; z=1,2 compacted by sidx.
// ---------------------------------------------------------------------------
__global__ __launch_bounds__(256) void cvt_gather(
    const float* __restrict__ xq, const float* __restrict__ xk, const float* __restrict__ xv,
    const int* __restrict__ sidx, const int* __restrict__ cnt,
    bf16* __restrict__ oq, bf16* __restrict__ ok, bf16* __restrict__ ov)
{
    const int z = blockIdx.y;
    const float* src = (z == 0) ? xq : (z == 1) ? xk : xv;
    bf16*        dst = (z == 0) ? oq : (z == 1) ? ok : ov;

    const int tid = threadIdx.x;
    const int rm  = blockIdx.x * 2 + (tid >> 7);   // dest row
    int srow = rm;
    if (z != 0) {
        const int cs = rm >> 1, b = rm & 1;
        if (cs >= cnt[0]) return;                  // uniform per block
        srow = sidx[cs] * 2 + b;
    }
    const int col = (tid & 127) * 8;
    const floatx4* sp = (const floatx4*)(src + (size_t)srow * D_ + col);
    floatx4 x0 = sp[0], x1 = sp[1];
    bf16x8 v;
    #pragma unroll
    for (int j = 0; j < 4; j++) { v[j] = (bf16)x0[j]; v[4 + j] = (bf16)x1[j]; }
    *(bf16x8*)(dst + (size_t)rm * D_ + col) = v;
}

// ---------------------------------------------------------------------------
// W fp32 -> bf16
// ---------------------------------------------------------------------------
__global__ __launch_bounds__(256) void cvt3(
    const float* __restrict__ a, const float* __restrict__ b, const float* __restrict__ c,
    bf16* __restrict__ oa, bf16* __restrict__ ob, bf16* __restrict__ oc)
{
    const int z = blockIdx.z;
    const float* src = (z == 0) ? a : (z == 1) ? b : c;
    bf16*        dst = (z == 0) ? oa : (z == 1) ? ob : oc;
    const size_t i = ((size_t)blockIdx.x * 256 + threadIdx.x) * 8;
    floatx4 x0 = *(const floatx4*)(src + i);
    floatx4 x1 = *(const floatx4*)(src + i + 4);
    bf16x8 v;
    #pragma unroll
    for (int j = 0; j < 4; j++) { v[j] = (bf16)x0[j]; v[4 + j] = (bf16)x1[j]; }
    *(bf16x8*)(dst + i) = v;
}

#define TM 128
#define TN 128
#define BK 64

// ---------------------------------------------------------------------------
// Fused QKV GEMM v4 (verified R16): counted-vmcnt 2-deep pipeline, BK=64,
// raw s_barrier, explicit waits, both-sides chunk swizzle.
//   z=0: Q[bh][s][hd]   = (X_q W_q^T + b_q) * QSCALE      (full 4096 rows)
//   z=1: K[bh][cs][hd]  =  X_kc W_k^T + b_k               (2*cnt rows)
//   z=2: VT[bh][hd][cs] =  X_vc W_v^T + b_v, via operand swap (2*cnt rows)
// ---------------------------------------------------------------------------
__global__ __launch_bounds__(256) void qkv_gemm_async(
    const bf16* __restrict__ xq, const bf16* __restrict__ xk, const bf16* __restrict__ xv,
    const bf16* __restrict__ wq, const bf16* __restrict__ wk, const bf16* __restrict__ wv,
    const float* __restrict__ bq, const float* __restrict__ bk, const float* __restrict__ bv,
    const int* __restrict__ cnt,
    bf16* __restrict__ oq, bf16* __restrict__ ok, bf16* __restrict__ ov)
{
    __shared__ __align__(16) bf16 a_lds[2][TM * BK];   // X tiles, 2 x 16 KB
    __shared__ __align__(16) bf16 b_lds[2][TN * BK];   // W tiles, 2 x 16 KB

    const int z = blockIdx.y;
    const bf16*  X  = (z == 0) ? xq : (z == 1) ? xk : xv;
    const bf16*  W  = (z == 0) ? wq : (z == 1) ? wk : wv;
    const float* Bi = (z == 0) ? bq : (z == 1) ? bk : bv;
    bf16*        O  = (z == 0) ? oq : (z == 1) ? ok : ov;

    // XCD swizzle: id%8 -> XCD (round-robin). XCD k gets mb in {k,8+k,16+k,24+k}
    const int f   = blockIdx.x;
    const int xcd = f & 7, t = f >> 3;
    const int m0  = ((t & 3) * 8 + xcd) * TM;
    const int n0  = (t >> 2) * TN;

    const int rows_active = (z == 0) ? M_ : 2 * cnt[0];
    if (m0 >= rows_active) return;

    const int tid  = threadIdx.x;
    const int wid  = tid >> 6;
    const int lane = tid & 63;
    const int wm = wid >> 1, wn = wid & 1;
    const int lm = lane & 15, lq = lane >> 4;

    // z==2: swap A/B so MFMA emits V^T (C-row = W-row = d, C-col = X-row = key)
    const int a_base = ((z == 2) ? wn : wm) * 64;
    const int b_base = ((z == 2) ? wm : wn) * 64;

    // staging precompute: 1024 chunks/tile/matrix, 4 per thread per matrix.
    // chunk c -> row=c>>3, swizzled k-chunk kcs=(c&7)^((c>>3)&7)
    const bf16* xs[4];
    const bf16* ws[4];
    int la[4];
    #pragma unroll
    for (int q = 0; q < 4; q++) {
        const int c   = (q * 4 + wid) * 64 + lane;
        const int row = c >> 3;
        const int kcs = ((c & 7) ^ (row & 7)) * 8;
        xs[q] = X + (size_t)(m0 + row) * D_ + kcs;
        ws[q] = W + (size_t)(n0 + row) * D_ + kcs;
        la[q] = (q * 4 + wid) * 512;   // wave-uniform LDS elem offset (64 ch x 8)
    }

    #define GEMM_STAGE(buf, kt)                                   \
        {                                                         \
            _Pragma("unroll")                                     \
            for (int q = 0; q < 4; q++) {                         \
                async_cp16(xs[q] + (kt), &a_lds[buf][la[q]]);     \
                async_cp16(ws[q] + (kt), &b_lds[buf][la[q]]);     \
            }                                                     \
        }

    floatx4 acc[4][4] = {};

    // prologue: 2 tiles in flight (16 loads/thread)
    GEMM_STAGE(0, 0);
    GEMM_STAGE(1, BK);

    const int nk = D_ / BK;   // 16
    for (int ki = 0; ki < nk; ki++) {
        const int cur = ki & 1;

        // own tile-ki loads landed (tile ki+1's 8 loads stay in flight)
        if (ki + 1 < nk) asm volatile("s_waitcnt vmcnt(8)" ::: "memory");
        else             asm volatile("s_waitcnt vmcnt(0)" ::: "memory");
        __builtin_amdgcn_sched_barrier(0);
        __builtin_amdgcn_s_barrier();          // tile-ki landed block-wide
        __builtin_amdgcn_sched_barrier(0);

        const bf16* src_a = (z == 2) ? b_lds[cur] : a_lds[cur];
        const bf16* src_b = (z == 2) ? a_lds[cur] : b_lds[cur];

        // all 16 fragments of buf[cur] -> regs (must complete before barrier 2)
        bf16x8 af[4][2], bfv[4][2];
        #pragma unroll
        for (int i = 0; i < 4; i++) {
            const int r = a_base + i * 16 + lm;
            #pragma unroll
            for (int ks = 0; ks < 2; ks++)
                af[i][ks] = *(const bf16x8*)(src_a + r * BK +
                                (((ks * 4 + lq) ^ (r & 7)) * 8));
        }
        #pragma unroll
        for (int j = 0; j < 4; j++) {
            const int r = b_base + j * 16 + lm;
            #pragma unroll
            for (int ks = 0; ks < 2; ks++)
                bfv[j][ks] = *(const bf16x8*)(src_b + r * BK +
                                (((ks * 4 + lq) ^ (r & 7)) * 8));
        }
        asm volatile("s_waitcnt lgkmcnt(0)" ::: "memory");   // reads in regs
        __builtin_amdgcn_sched_barrier(0);                   // rule #18 fence
        __builtin_amdgcn_s_barrier();          // all reads of buf[cur] done
        __builtin_amdgcn_sched_barrier(0);

        // refill the just-freed buffer (issue before MFMA for overlap)
        if (ki + 2 < nk) GEMM_STAGE(cur, (ki + 2) * BK);

        __builtin_amdgcn_s_setprio(1);
        #pragma unroll
        for (int ks = 0; ks < 2; ks++)
            #pragma unroll
            for (int i = 0; i < 4; i++)
                #pragma unroll
                for (int j = 0; j < 4; j++)
                    acc[i][j] = __builtin_amdgcn_mfma_f32_16x16x32_bf16(
                        af[i][ks], bfv[j][ks], acc[i][j], 0, 0, 0);
        __builtin_amdgcn_s_setprio(0);
    }
    #undef GEMM_STAGE

    // C/D layout: col = lane&15 (B-side), row = lq*4 + reg (A-side).
    if (z != 2) {
        #pragma unroll
        for (int j = 0; j < 4; j++) {
            const int n = n0 + wn * 64 + j * 16 + lm;          // W row
            const float bias = Bi[n];
            const int h = n >> 6, hd = n & 63;
            #pragma unroll
            for (int i = 0; i < 4; i++) {
                const int mb = m0 + wm * 64 + i * 16 + lq * 4;
                #pragma unroll
                for (int r = 0; r < 4; r++) {
                    const int m = mb + r;                      // X row
                    const int row = m >> 1, b = m & 1;         // s or cs
                    float v = acc[i][j][r] + bias;
                    if (z == 0) v *= QSCALE;
                    O[(((size_t)(b * H_ + h)) * S_ + row) * HD_ + hd] = (bf16)v;
                }
            }
        }
    } else {
        #pragma unroll
        for (int j = 0; j < 4; j++) {
            const int m = m0 + wm * 64 + j * 16 + lm;          // X row (key)
            const int cs = m >> 1, b = m & 1;
            #pragma unroll
            for (int i = 0; i < 4; i++) {
                const int wb = n0 + wn * 64 + i * 16 + lq * 4;
                #pragma unroll
                for (int r = 0; r < 4; r++) {
                    const int n = wb + r;                      // W row
                    const float bias = Bi[n];
                    const int h = n >> 6, d = n & 63;
                    O[(((size_t)(b * H_ + h)) * HD_ + d) * S_ + cs] =
                        (bf16)(acc[i][j][r] + bias);
                }
            }
        }
    }
}

// ---------------------------------------------------------------------------
// MFMA flash attention over cnt compacted keys. K[bh][cs][d], VT[bh][d][cs].
// v7.1 == verified v7 (QB=128, 2 Q-tiles/wave, dbuf K/V, async-stage,
// 1 barrier/KV-tile, wave-local lgkmcnt for P, setprio, native exp2,
// XCD bh-affinity) + tail-hoisted masked select (sync-neutral).
// ---------------------------------------------------------------------------
#define KT 64
#define QB 128

__global__ __launch_bounds__(256) void attn_kernel(
    const bf16* __restrict__ qw, const bf16* __restrict__ kw, const bf16* __restrict__ vtw,
    const int* __restrict__ cnt, float* __restrict__ out)
{
    __shared__ __align__(16) bf16 k_lds[2 * KT * HD_];      // [buf][kj][d], 16 KB
    __shared__ __align__(16) bf16 v_ldsT[2 * HD_ * KT];     // [buf][d][kj], 16 KB
    __shared__ __align__(16) bf16 p_lds[4 * 2 * 16 * 72];   // [wave][tile][row][72], 18 KB

    const int tid  = threadIdx.x;
    const int wid  = tid >> 6;
    const int lane = tid & 63;
    const int lm = lane & 15, lq = lane >> 4;

    // XCD bh-affinity: id%8 -> XCD (round-robin); XCD x owns bh in
    // {4x..4x+3}, all 16 q-blocks of each bh -> K/V L2-resident per XCD.
    const int id  = blockIdx.x;
    const int j   = id >> 3;
    const int bh  = (id & 7) * 4 + (j >> 4);
    const int q0  = (j & 15) * QB;
    const int count = cnt[0];

    const bf16* Qb  = qw  + (size_t)bh * S_ * HD_;
    const bf16* Kb  = kw  + (size_t)bh * S_ * HD_;
    const bf16* VTb = vtw + (size_t)bh * HD_ * S_;

    // Q fragments: two 16-row tiles per wave (rows q0 + wid*32 + t*16 + lm)
    bf16x8 qf[2][2];
    #pragma unroll
    for (int t = 0; t < 2; t++) {
        const bf16* qp = Qb + (size_t)(q0 + wid * 32 + t * 16 + lm) * HD_;
        qf[t][0] = *(const bf16x8*)(qp + lq * 8);
        qf[t][1] = *(const bf16x8*)(qp + 32 + lq * 8);
    }

    float lsum[2][4] = {};
    floatx4 oacc[2][4] = {};
    bf16* pwb = p_lds + wid * (2 * 16 * 72);

    // staging geometry: 512 16B-chunks per 64x64 tile, 2 per thread
    const int c0row = tid >> 3, c0ch = tid & 7;          // chunk tid
    const int c1row = (tid + 256) >> 3, c1ch = tid & 7;  // chunk tid+256

    // prologue: stage tile 0 into buf 0
    {
        bf16x8 kv0 = *(const bf16x8*)(Kb + (size_t)c0row * HD_ + c0ch * 8);
        bf16x8 kv1 = *(const bf16x8*)(Kb + (size_t)c1row * HD_ + c1ch * 8);
        bf16x8 vv0 = *(const bf16x8*)(VTb + (size_t)c0row * S_ + c0ch * 8);
        bf16x8 vv1 = *(const bf16x8*)(VTb + (size_t)c1row * S_ + c1ch * 8);
        *(bf16x8*)(k_lds + c0row * 64 + ((c0ch ^ (c0row & 7)) * 8)) = kv0;
        *(bf16x8*)(k_lds + c1row * 64 + ((c1ch ^ (c1row & 7)) * 8)) = kv1;
        *(bf16x8*)(v_ldsT + c0row * 64 + ((c0ch ^ (c0row & 7)) * 8)) = vv0;
        *(bf16x8*)(v_ldsT + c1row * 64 + ((c1ch ^ (c1row & 7)) * 8)) = vv1;
    }
    __syncthreads();

    const int nt = (count + KT - 1) / KT;
    for (int it = 0; it < nt; ++it) {
        const int j0  = it * KT;
        const int cur = it & 1, nxt = cur ^ 1;
        const bool has_next = (it + 1 < nt);
        const bool tail = (j0 + KT > count);       // wave-uniform
        const bf16* kc = k_lds + cur * (KT * 64);
        const bf16* vc = v_ldsT + cur * (KT * 64);

        // T14 async-STAGE: issue next tile's global loads now, LDS-write after PV
        bf16x8 kreg0, kreg1, vreg0, vreg1;
        if (has_next) {
            const int jn = j0 + KT;
            kreg0 = *(const bf16x8*)(Kb + (size_t)(jn + c0row) * HD_ + c0ch * 8);
            kreg1 = *(const bf16x8*)(Kb + (size_t)(jn + c1row) * HD_ + c1ch * 8);
            vreg0 = *(const bf16x8*)(VTb + (size_t)c0row * S_ + jn + c0ch * 8);
            vreg1 = *(const bf16x8*)(VTb + (size_t)c1row * S_ + jn + c1ch * 8);
        }

        // QK^T: k-fragment shared across both Q tiles
        floatx4 sacc[2][4] = {};
        __builtin_amdgcn_s_setprio(1);
        #pragma unroll
        for (int ks = 0; ks < 2; ks++)
            #pragma unroll
            for (int n = 0; n < 4; n++) {
                bf16x8 kf = *(const bf16x8*)(kc + (n * 16 + lm) * 64 +
                                             (((ks * 4 + lq) ^ (lm & 7)) * 8));
                sacc[0][n] = __builtin_amdgcn_mfma_f32_16x16x32_bf16(qf[0][ks], kf, sacc[0][n], 0, 0, 0);
                sacc[1][n] = __builtin_amdgcn_mfma_f32_16x16x32_bf16(qf[1][ks], kf, sacc[1][n], 0, 0, 0);
            }
        __builtin_amdgcn_s_setprio(0);

        // p = exp2(score) via native v_exp_f32. Tail tile only: select
        // (not multiply) past count so garbage K rows can't poison lsum.
        if (!tail) {
            #pragma unroll
            for (int t = 0; t < 2; t++)
                #pragma unroll
                for (int r = 0; r < 4; r++)
                    #pragma unroll
                    for (int n = 0; n < 4; n++) {
                        const float p = EXP2F(sacc[t][n][r]);
                        lsum[t][r] += p;
                        pwb[t * (16 * 72) + (lq * 4 + r) * 72 + n * 16 + lm] = (bf16)p;
                    }
        } else {
            bool valid[4];
            #pragma unroll
            for (int n = 0; n < 4; n++)
                valid[n] = (j0 + n * 16 + lm < count);
            #pragma unroll
            for (int t = 0; t < 2; t++)
                #pragma unroll
                for (int r = 0; r < 4; r++)
                    #pragma unroll
                    for (int n = 0; n < 4; n++) {
                        const float p = valid[n] ? EXP2F(sacc[t][n][r]) : 0.0f;
                        lsum[t][r] += p;
                        pwb[t * (16 * 72) + (lq * 4 + r) * 72 + n * 16 + lm] = (bf16)p;
                    }
        }

        // p_lds is per-wave: wave-local drain is enough (no block barrier).
        asm volatile("s_waitcnt lgkmcnt(0)" ::: "memory");
        __builtin_amdgcn_sched_barrier(0);

        // PV (A = P, B = V^T rows); v-fragment shared across both Q tiles
        __builtin_amdgcn_s_setprio(1);
        #pragma unroll
        for (int ks = 0; ks < 2; ks++) {
            bf16x8 pf0 = *(const bf16x8*)(pwb + lm * 72 + ks * 32 + lq * 8);
            bf16x8 pf1 = *(const bf16x8*)(pwb + (16 * 72) + lm * 72 + ks * 32 + lq * 8);
            #pragma unroll
            for (int n = 0; n < 4; n++) {
                bf16x8 vf = *(const bf16x8*)(vc + (n * 16 + lm) * 64 +
                                             (((ks * 4 + lq) ^ (lm & 7)) * 8));
                oacc[0][n] = __builtin_amdgcn_mfma_f32_16x16x32_bf16(pf0, vf, oacc[0][n], 0, 0, 0);
                oacc[1][n] = __builtin_amdgcn_mfma_f32_16x16x32_bf16(pf1, vf, oacc[1][n], 0, 0, 0);
            }
        }
        __builtin_amdgcn_s_setprio(0);

        // write staged regs into the other buffer (nobody reads it: barrier at
        // end of prev iter guaranteed all reads of buf[nxt] completed)
        if (has_next) {
            bf16* kd = k_lds + nxt * (KT * 64);
            bf16* vd = v_ldsT + nxt * (KT * 64);
            *(bf16x8*)(kd + c0row * 64 + ((c0ch ^ (c0row & 7)) * 8)) = kreg0;
            *(bf16x8*)(kd + c1row * 64 + ((c1ch ^ (c1row & 7)) * 8)) = kreg1;
            *(bf16x8*)(vd + c0row * 64 + ((c0ch ^ (c0row & 7)) * 8)) = vreg0;
            *(bf16x8*)(vd + c1row * 64 + ((c1ch ^ (c1row & 7)) * 8)) = vreg1;
        }
        __syncthreads();   // one barrier per KV-tile
    }

    float invl[2][4];
    #pragma unroll
    for (int t = 0; t < 2; t++)
        #pragma unroll
        for (int r = 0; r < 4; r++) {
            float lr = lsum[t][r];
            lr += __shfl_xor(lr, 1);
            lr += __shfl_xor(lr, 2);
            lr += __shfl_xor(lr, 4);
            lr += __shfl_xor(lr, 8);
            invl[t][r] = 1.0f / lr;
        }
    const int b = bh >> 4, h = bh & 15;
    #pragma unroll
    for (int t = 0; t < 2; t++)
        #pragma unroll
        for (int n = 0; n < 4; n++)
            #pragma unroll
            for (int r = 0; r < 4; r++) {
                const int q = q0 + wid * 32 + t * 16 + lq * 4 + r;
                out[((size_t)q * B_ + b) * D_ + h * 64 + n * 16 + lm] =
                    oacc[t][n][r] * invl[t][r];
            }
}

// ---------------------------------------------------------------------------
extern "C" void kernel_launch(void* const* d_in, const int* in_sizes, int n_in,
                              void* d_out, int out_size, void* d_ws, size_t ws_size,
                              hipStream_t stream) {
    const float* xq = (const float*)d_in[0];
    const float* xk = (const float*)d_in[1];
    const float* xv = (const float*)d_in[2];
    const int*  mask = (const int*)d_in[3];
    const float* wq = (const float*)d_in[4];
    const float* bq = (const float*)d_in[5];
    const float* wk = (const float*)d_in[6];
    const float* bk = (const float*)d_in[7];
    const float* wv = (const float*)d_in[8];
    const float* bv = (const float*)d_in[9];

    const size_t NX = (size_t)M_ * D_;      // 4194304
    const size_t NW = (size_t)D_ * D_;      // 1048576
    char* ws = (char*)d_ws;
    int* cnt  = (int*)ws;
    int* sidx = cnt + 16;
    char* base = ws + 16384;

    bf16* xqb = (bf16*)base;
    bf16* xkb = xqb + NX;
    bf16* xvb = xkb + NX;
    bf16* wqb = xvb + NX;
    bf16* wkb = wqb + NW;
    bf16* wvb = wkb + NW;
    bf16* q_ws  = wvb + NW;
    bf16* k_ws  = q_ws + NX;
    bf16* vt_ws = k_ws + NX;

    mask_scan<<<1, 256, 0, stream>>>(mask, sidx, cnt);
    cvt_gather<<<dim3(M_ / 2, 3), 256, 0, stream>>>(xq, xk, xv, sidx, cnt,
                                                    xqb, xkb, xvb);
    cvt3<<<dim3(NW / 2048, 1, 3), 256, 0, stream>>>(wq, wk, wv, wqb, wkb, wvb);

    qkv_gemm_async<<<dim3(256, 3), 256, 0, stream>>>(xqb, xkb, xvb, wqb, wkb, wvb,
                                                     bq, bk, bv, cnt,
                                                     q_ws, k_ws, vt_ws);

    attn_kernel<<<dim3((S_ / QB) * B_ * H_), 256, 0, stream>>>(q_ws, k_ws, vt_ws,
                                                               cnt, (float*)d_out);
}

// Round 19
// 178.965 us; speedup vs baseline: 1.0789x; 1.0059x over previous
//
#include <hip/hip_runtime.h>
#include <stdint.h>

// MultiHeadAttention: S=2048 B=2 D=1024 H=16 HD=64 — fp32 in/out.
// Round 24 == Round 20 resubmit (four infra failures; attn v9 unmeasured).
//   attn v9 = 512-thread blocks (8 waves x 1 Q-tile), QB=128 kept.
//   R17 lesson: staging is per-block & QB-bound -> keep QB=128; R19 counters
//   show attn latency-bound at 8 waves/CU. v9 doubles waves/CU (16) at
//   IDENTICAL per-block staging traffic/barriers. Inner loop = R17's
//   correctness-verified per-wave code; decode/sync = verified v7.
//   - qkv_gemm_async v4 (verified R16): counted-vmcnt 2-deep, BK=64. Frozen.
//   - cvt/scan unchanged.

#define S_ 2048
#define B_ 2
#define D_ 1024
#define H_ 16
#define HD_ 64
#define M_ (S_ * B_)

typedef __bf16 bf16;
typedef bf16 bf16x8 __attribute__((ext_vector_type(8)));
typedef float floatx4 __attribute__((ext_vector_type(4)));

#define QSCALE 0.18033688011112042f   // (1/sqrt(64)) * log2(e)

#if __has_builtin(__builtin_amdgcn_exp2f)
#define EXP2F(x) __builtin_amdgcn_exp2f(x)
#else
#define EXP2F(x) exp2f(x)
#endif

__device__ __forceinline__ void async_cp16(const bf16* g, bf16* l) {
    __builtin_amdgcn_global_load_lds(
        (const __attribute__((address_space(1))) void*)g,
        (__attribute__((address_space(3))) void*)l, 16, 0, 0);
}

// ---------------------------------------------------------------------------
// mask scan: cnt = #unmasked, sidx[p] = p-th unmasked s (ascending)
// ---------------------------------------------------------------------------
__global__ __launch_bounds__(256) void mask_scan(const int* __restrict__ mask,
                                                 int* __restrict__ sidx,
                                                 int* __restrict__ cnt)
{
    __shared__ int sums[256];
    const int tid = threadIdx.x;
    int v[8], s = 0;
    #pragma unroll
    for (int j = 0; j < 8; j++) { v[j] = mask[tid * 8 + j] ? 1 : 0; s += v[j]; }
    sums[tid] = s;
    __syncthreads();
    for (int off = 1; off < 256; off <<= 1) {
        int t = (tid >= off) ? sums[tid - off] : 0;
        __syncthreads();
        sums[tid] += t;
        __syncthreads();
    }
    int base = (tid > 0) ? sums[tid - 1] : 0;
    #pragma unroll
    for (int j = 0; j < 8; j++)
        if (v[j]) { sidx[base] = tid * 8 + j; base++; }
    if (tid == 255) cnt[0] = sums[255];
}

// ---------------------------------------------------------------------------
// X convert (+gather for K/V): z=0 straight; z=1,2 compacted by sidx.
// ---------------------------------------------------------------------------
__global__ __launch_bounds__(256) void cvt_gather(
    const float* __restrict__ xq, const float* __restrict__ xk, const float* __restrict__ xv,
    const int* __restrict__ sidx, const int* __restrict__ cnt,
    bf16* __restrict__ oq, bf16* __restrict__ ok, bf16* __restrict__ ov)
{
    const int z = blockIdx.y;
    const float* src = (z == 0) ? xq : (z == 1) ? xk : xv;
    bf16*        dst = (z == 0) ? oq : (z == 1) ? ok : ov;

    const int tid = threadIdx.x;
    const int rm  = blockIdx.x * 2 + (tid >> 7);   // dest row
    int srow = rm;
    if (z != 0) {
        const int cs = rm >> 1, b = rm & 1;
        if (cs >= cnt[0]) return;                  // uniform per block
        srow = sidx[cs] * 2 + b;
    }
    const int col = (tid & 127) * 8;
    const floatx4* sp = (const floatx4*)(src + (size_t)srow * D_ + col);
    floatx4 x0 = sp[0], x1 = sp[1];
    bf16x8 v;
    #pragma unroll
    for (int j = 0; j < 4; j++) { v[j] = (bf16)x0[j]; v[4 + j] = (bf16)x1[j]; }
    *(bf16x8*)(dst + (size_t)rm * D_ + col) = v;
}

// ---------------------------------------------------------------------------
// W fp32 -> bf16
// ---------------------------------------------------------------------------
__global__ __launch_bounds__(256) void cvt3(
    const float* __restrict__ a, const float* __restrict__ b, const float* __restrict__ c,
    bf16* __restrict__ oa, bf16* __restrict__ ob, bf16* __restrict__ oc)
{
    const int z = blockIdx.z;
    const float* src = (z == 0) ? a : (z == 1) ? b : c;
    bf16*        dst = (z == 0) ? oa : (z == 1) ? ob : oc;
    const size_t i = ((size_t)blockIdx.x * 256 + threadIdx.x) * 8;
    floatx4 x0 = *(const floatx4*)(src + i);
    floatx4 x1 = *(const floatx4*)(src + i + 4);
    bf16x8 v;
    #pragma unroll
    for (int j = 0; j < 4; j++) { v[j] = (bf16)x0[j]; v[4 + j] = (bf16)x1[j]; }
    *(bf16x8*)(dst + i) = v;
}

#define TM 128
#define TN 128
#define BK 64

// ---------------------------------------------------------------------------
// Fused QKV GEMM v4 (verified R16): counted-vmcnt 2-deep pipeline, BK=64,
// raw s_barrier, explicit waits, both-sides chunk swizzle.
//   z=0: Q[bh][s][hd]   = (X_q W_q^T + b_q) * QSCALE      (full 4096 rows)
//   z=1: K[bh][cs][hd]  =  X_kc W_k^T + b_k               (2*cnt rows)
//   z=2: VT[bh][hd][cs] =  X_vc W_v^T + b_v, via operand swap (2*cnt rows)
// ---------------------------------------------------------------------------
__global__ __launch_bounds__(256) void qkv_gemm_async(
    const bf16* __restrict__ xq, const bf16* __restrict__ xk, const bf16* __restrict__ xv,
    const bf16* __restrict__ wq, const bf16* __restrict__ wk, const bf16* __restrict__ wv,
    const float* __restrict__ bq, const float* __restrict__ bk, const float* __restrict__ bv,
    const int* __restrict__ cnt,
    bf16* __restrict__ oq, bf16* __restrict__ ok, bf16* __restrict__ ov)
{
    __shared__ __align__(16) bf16 a_lds[2][TM * BK];   // X tiles, 2 x 16 KB
    __shared__ __align__(16) bf16 b_lds[2][TN * BK];   // W tiles, 2 x 16 KB

    const int z = blockIdx.y;
    const bf16*  X  = (z == 0) ? xq : (z == 1) ? xk : xv;
    const bf16*  W  = (z == 0) ? wq : (z == 1) ? wk : wv;
    const float* Bi = (z == 0) ? bq : (z == 1) ? bk : bv;
    bf16*        O  = (z == 0) ? oq : (z == 1) ? ok : ov;

    // XCD swizzle: id%8 -> XCD (round-robin). XCD k gets mb in {k,8+k,16+k,24+k}
    const int f   = blockIdx.x;
    const int xcd = f & 7, t = f >> 3;
    const int m0  = ((t & 3) * 8 + xcd) * TM;
    const int n0  = (t >> 2) * TN;

    const int rows_active = (z == 0) ? M_ : 2 * cnt[0];
    if (m0 >= rows_active) return;

    const int tid  = threadIdx.x;
    const int wid  = tid >> 6;
    const int lane = tid & 63;
    const int wm = wid >> 1, wn = wid & 1;
    const int lm = lane & 15, lq = lane >> 4;

    // z==2: swap A/B so MFMA emits V^T (C-row = W-row = d, C-col = X-row = key)
    const int a_base = ((z == 2) ? wn : wm) * 64;
    const int b_base = ((z == 2) ? wm : wn) * 64;

    // staging precompute: 1024 chunks/tile/matrix, 4 per thread per matrix.
    // chunk c -> row=c>>3, swizzled k-chunk kcs=(c&7)^((c>>3)&7)
    const bf16* xs[4];
    const bf16* ws[4];
    int la[4];
    #pragma unroll
    for (int q = 0; q < 4; q++) {
        const int c   = (q * 4 + wid) * 64 + lane;
        const int row = c >> 3;
        const int kcs = ((c & 7) ^ (row & 7)) * 8;
        xs[q] = X + (size_t)(m0 + row) * D_ + kcs;
        ws[q] = W + (size_t)(n0 + row) * D_ + kcs;
        la[q] = (q * 4 + wid) * 512;   // wave-uniform LDS elem offset (64 ch x 8)
    }

    #define GEMM_STAGE(buf, kt)                                   \
        {                                                         \
            _Pragma("unroll")                                     \
            for (int q = 0; q < 4; q++) {                         \
                async_cp16(xs[q] + (kt), &a_lds[buf][la[q]]);     \
                async_cp16(ws[q] + (kt), &b_lds[buf][la[q]]);     \
            }                                                     \
        }

    floatx4 acc[4][4] = {};

    // prologue: 2 tiles in flight (16 loads/thread)
    GEMM_STAGE(0, 0);
    GEMM_STAGE(1, BK);

    const int nk = D_ / BK;   // 16
    for (int ki = 0; ki < nk; ki++) {
        const int cur = ki & 1;

        // own tile-ki loads landed (tile ki+1's 8 loads stay in flight)
        if (ki + 1 < nk) asm volatile("s_waitcnt vmcnt(8)" ::: "memory");
        else             asm volatile("s_waitcnt vmcnt(0)" ::: "memory");
        __builtin_amdgcn_sched_barrier(0);
        __builtin_amdgcn_s_barrier();          // tile-ki landed block-wide
        __builtin_amdgcn_sched_barrier(0);

        const bf16* src_a = (z == 2) ? b_lds[cur] : a_lds[cur];
        const bf16* src_b = (z == 2) ? a_lds[cur] : b_lds[cur];

        // all 16 fragments of buf[cur] -> regs (must complete before barrier 2)
        bf16x8 af[4][2], bfv[4][2];
        #pragma unroll
        for (int i = 0; i < 4; i++) {
            const int r = a_base + i * 16 + lm;
            #pragma unroll
            for (int ks = 0; ks < 2; ks++)
                af[i][ks] = *(const bf16x8*)(src_a + r * BK +
                                (((ks * 4 + lq) ^ (r & 7)) * 8));
        }
        #pragma unroll
        for (int j = 0; j < 4; j++) {
            const int r = b_base + j * 16 + lm;
            #pragma unroll
            for (int ks = 0; ks < 2; ks++)
                bfv[j][ks] = *(const bf16x8*)(src_b + r * BK +
                                (((ks * 4 + lq) ^ (r & 7)) * 8));
        }
        asm volatile("s_waitcnt lgkmcnt(0)" ::: "memory");   // reads in regs
        __builtin_amdgcn_sched_barrier(0);                   // rule #18 fence
        __builtin_amdgcn_s_barrier();          // all reads of buf[cur] done
        __builtin_amdgcn_sched_barrier(0);

        // refill the just-freed buffer (issue before MFMA for overlap)
        if (ki + 2 < nk) GEMM_STAGE(cur, (ki + 2) * BK);

        __builtin_amdgcn_s_setprio(1);
        #pragma unroll
        for (int ks = 0; ks < 2; ks++)
            #pragma unroll
            for (int i = 0; i < 4; i++)
                #pragma unroll
                for (int j = 0; j < 4; j++)
                    acc[i][j] = __builtin_amdgcn_mfma_f32_16x16x32_bf16(
                        af[i][ks], bfv[j][ks], acc[i][j], 0, 0, 0);
        __builtin_amdgcn_s_setprio(0);
    }
    #undef GEMM_STAGE

    // C/D layout: col = lane&15 (B-side), row = lq*4 + reg (A-side).
    if (z != 2) {
        #pragma unroll
        for (int j = 0; j < 4; j++) {
            const int n = n0 + wn * 64 + j * 16 + lm;          // W row
            const float bias = Bi[n];
            const int h = n >> 6, hd = n & 63;
            #pragma unroll
            for (int i = 0; i < 4; i++) {
                const int mb = m0 + wm * 64 + i * 16 + lq * 4;
                #pragma unroll
                for (int r = 0; r < 4; r++) {
                    const int m = mb + r;                      // X row
                    const int row = m >> 1, b = m & 1;         // s or cs
                    float v = acc[i][j][r] + bias;
                    if (z == 0) v *= QSCALE;
                    O[(((size_t)(b * H_ + h)) * S_ + row) * HD_ + hd] = (bf16)v;
                }
            }
        }
    } else {
        #pragma unroll
        for (int j = 0; j < 4; j++) {
            const int m = m0 + wm * 64 + j * 16 + lm;          // X row (key)
            const int cs = m >> 1, b = m & 1;
            #pragma unroll
            for (int i = 0; i < 4; i++) {
                const int wb = n0 + wn * 64 + i * 16 + lq * 4;
                #pragma unroll
                for (int r = 0; r < 4; r++) {
                    const int n = wb + r;                      // W row
                    const float bias = Bi[n];
                    const int h = n >> 6, d = n & 63;
                    O[(((size_t)(b * H_ + h)) * HD_ + d) * S_ + cs] =
                        (bf16)(acc[i][j][r] + bias);
                }
            }
        }
    }
}

// ---------------------------------------------------------------------------
// MFMA flash attention over cnt compacted keys. K[bh][cs][d], VT[bh][d][cs].
// v9: 512 threads = 8 waves x 1 Q-tile (16 rows), QB=128 per block kept
// (same staging amortization as verified v7). Per-wave inner loop = R17's
// correctness-verified v8 code. Dbuf K/V, async-stage, 1 barrier/KV-tile,
// wave-local lgkmcnt for P, setprio, native exp2, XCD bh-affinity,
// tail-hoisted masked select.
// ---------------------------------------------------------------------------
#define KT 64
#define QB 128

__global__ __launch_bounds__(512) void attn_kernel(
    const bf16* __restrict__ qw, const bf16* __restrict__ kw, const bf16* __restrict__ vtw,
    const int* __restrict__ cnt, float* __restrict__ out)
{
    __shared__ __align__(16) bf16 k_lds[2 * KT * HD_];      // [buf][kj][d], 16 KB
    __shared__ __align__(16) bf16 v_ldsT[2 * HD_ * KT];     // [buf][d][kj], 16 KB
    __shared__ __align__(16) bf16 p_lds[8 * 16 * 72];       // [wave][row][72], 18 KB

    const int tid  = threadIdx.x;
    const int wid  = tid >> 6;          // 0..7
    const int lane = tid & 63;
    const int lm = lane & 15, lq = lane >> 4;

    // XCD bh-affinity: id%8 -> XCD (round-robin); XCD x owns bh in
    // {4x..4x+3}, all 16 q-blocks of each bh -> K/V L2-resident per XCD.
    const int id  = blockIdx.x;
    const int j   = id >> 3;
    const int bh  = (id & 7) * 4 + (j >> 4);
    const int q0  = (j & 15) * QB;
    const int count = cnt[0];

    const bf16* Qb  = qw  + (size_t)bh * S_ * HD_;
    const bf16* Kb  = kw  + (size_t)bh * S_ * HD_;
    const bf16* VTb = vtw + (size_t)bh * HD_ * S_;

    // Q fragments: one 16-row tile per wave (rows q0 + wid*16 + lm)
    bf16x8 qf[2];
    {
        const bf16* qp = Qb + (size_t)(q0 + wid * 16 + lm) * HD_;
        qf[0] = *(const bf16x8*)(qp + lq * 8);
        qf[1] = *(const bf16x8*)(qp + 32 + lq * 8);
    }

    float lsum[4] = {};
    floatx4 oacc[4] = {};
    bf16* pwb = p_lds + wid * (16 * 72);

    // staging geometry: 512 16B-chunks per 64x64 tile, 1 per thread
    const int c0row = tid >> 3, c0ch = tid & 7;

    // prologue: stage tile 0 into buf 0
    {
        bf16x8 kv0 = *(const bf16x8*)(Kb + (size_t)c0row * HD_ + c0ch * 8);
        bf16x8 vv0 = *(const bf16x8*)(VTb + (size_t)c0row * S_ + c0ch * 8);
        *(bf16x8*)(k_lds + c0row * 64 + ((c0ch ^ (c0row & 7)) * 8)) = kv0;
        *(bf16x8*)(v_ldsT + c0row * 64 + ((c0ch ^ (c0row & 7)) * 8)) = vv0;
    }
    __syncthreads();

    const int nt = (count + KT - 1) / KT;
    for (int it = 0; it < nt; ++it) {
        const int j0  = it * KT;
        const int cur = it & 1, nxt = cur ^ 1;
        const bool has_next = (it + 1 < nt);
        const bool tail = (j0 + KT > count);       // wave-uniform
        const bf16* kc = k_lds + cur * (KT * 64);
        const bf16* vc = v_ldsT + cur * (KT * 64);

        // T14 async-STAGE: issue next tile's global loads now, LDS-write after PV
        bf16x8 kreg0, vreg0;
        if (has_next) {
            const int jn = j0 + KT;
            kreg0 = *(const bf16x8*)(Kb + (size_t)(jn + c0row) * HD_ + c0ch * 8);
            vreg0 = *(const bf16x8*)(VTb + (size_t)c0row * S_ + jn + c0ch * 8);
        }

        // QK^T
        floatx4 sacc[4] = {};
        __builtin_amdgcn_s_setprio(1);
        #pragma unroll
        for (int ks = 0; ks < 2; ks++)
            #pragma unroll
            for (int n = 0; n < 4; n++) {
                bf16x8 kf = *(const bf16x8*)(kc + (n * 16 + lm) * 64 +
                                             (((ks * 4 + lq) ^ (lm & 7)) * 8));
                sacc[n] = __builtin_amdgcn_mfma_f32_16x16x32_bf16(qf[ks], kf, sacc[n], 0, 0, 0);
            }
        __builtin_amdgcn_s_setprio(0);

        // p = exp2(score) via native v_exp_f32. Tail tile only: select
        // (not multiply) past count so garbage K rows can't poison lsum.
        if (!tail) {
            #pragma unroll
            for (int r = 0; r < 4; r++)
                #pragma unroll
                for (int n = 0; n < 4; n++) {
                    const float p = EXP2F(sacc[n][r]);
                    lsum[r] += p;
                    pwb[(lq * 4 + r) * 72 + n * 16 + lm] = (bf16)p;
                }
        } else {
            bool valid[4];
            #pragma unroll
            for (int n = 0; n < 4; n++)
                valid[n] = (j0 + n * 16 + lm < count);
            #pragma unroll
            for (int r = 0; r < 4; r++)
                #pragma unroll
                for (int n = 0; n < 4; n++) {
                    const float p = valid[n] ? EXP2F(sacc[n][r]) : 0.0f;
                    lsum[r] += p;
                    pwb[(lq * 4 + r) * 72 + n * 16 + lm] = (bf16)p;
                }
        }

        // p_lds is per-wave: wave-local drain is enough (no block barrier).
        asm volatile("s_waitcnt lgkmcnt(0)" ::: "memory");
        __builtin_amdgcn_sched_barrier(0);

        // PV (A = P, B = V^T rows)
        __builtin_amdgcn_s_setprio(1);
        #pragma unroll
        for (int ks = 0; ks < 2; ks++) {
            bf16x8 pf = *(const bf16x8*)(pwb + lm * 72 + ks * 32 + lq * 8);
            #pragma unroll
            for (int n = 0; n < 4; n++) {
                bf16x8 vf = *(const bf16x8*)(vc + (n * 16 + lm) * 64 +
                                             (((ks * 4 + lq) ^ (lm & 7)) * 8));
                oacc[n] = __builtin_amdgcn_mfma_f32_16x16x32_bf16(pf, vf, oacc[n], 0, 0, 0);
            }
        }
        __builtin_amdgcn_s_setprio(0);

        // write staged regs into the other buffer (nobody reads it: barrier at
        // end of prev iter guaranteed all reads of buf[nxt] completed)
        if (has_next) {
            bf16* kd = k_lds + nxt * (KT * 64);
            bf16* vd = v_ldsT + nxt * (KT * 64);
            *(bf16x8*)(kd + c0row * 64 + ((c0ch ^ (c0row & 7)) * 8)) = kreg0;
            *(bf16x8*)(vd + c0row * 64 + ((c0ch ^ (c0row & 7)) * 8)) = vreg0;
        }
        __syncthreads();   // one barrier per KV-tile
    }

    float invl[4];
    #pragma unroll
    for (int r = 0; r < 4; r++) {
        float lr = lsum[r];
        lr += __shfl_xor(lr, 1);
        lr += __shfl_xor(lr, 2);
        lr += __shfl_xor(lr, 4);
        lr += __shfl_xor(lr, 8);
        invl[r] = 1.0f / lr;
    }
    const int b = bh >> 4, h = bh & 15;
    #pragma unroll
    for (int n = 0; n < 4; n++)
        #pragma unroll
        for (int r = 0; r < 4; r++) {
            const int q = q0 + wid * 16 + lq * 4 + r;
            out[((size_t)q * B_ + b) * D_ + h * 64 + n * 16 + lm] =
                oacc[n][r] * invl[r];
        }
}

// ---------------------------------------------------------------------------
extern "C" void kernel_launch(void* const* d_in, const int* in_sizes, int n_in,
                              void* d_out, int out_size, void* d_ws, size_t ws_size,
                              hipStream_t stream) {
    const float* xq = (const float*)d_in[0];
    const float* xk = (const float*)d_in[1];
    const float* xv = (const float*)d_in[2];
    const int*  mask = (const int*)d_in[3];
    const float* wq = (const float*)d_in[4];
    const float* bq = (const float*)d_in[5];
    const float* wk = (const float*)d_in[6];
    const float* bk = (const float*)d_in[7];
    const float* wv = (const float*)d_in[8];
    const float* bv = (const float*)d_in[9];

    const size_t NX = (size_t)M_ * D_;      // 4194304
    const size_t NW = (size_t)D_ * D_;      // 1048576
    char* ws = (char*)d_ws;
    int* cnt  = (int*)ws;
    int* sidx = cnt + 16;
    char* base = ws + 16384;

    bf16* xqb = (bf16*)base;
    bf16* xkb = xqb + NX;
    bf16* xvb = xkb + NX;
    bf16* wqb = xvb + NX;
    bf16* wkb = wqb + NW;
    bf16* wvb = wkb + NW;
    bf16* q_ws  = wvb + NW;
    bf16* k_ws  = q_ws + NX;
    bf16* vt_ws = k_ws + NX;

    mask_scan<<<1, 256, 0, stream>>>(mask, sidx, cnt);
    cvt_gather<<<dim3(M_ / 2, 3), 256, 0, stream>>>(xq, xk, xv, sidx, cnt,
                                                    xqb, xkb, xvb);
    cvt3<<<dim3(NW / 2048, 1, 3), 256, 0, stream>>>(wq, wk, wv, wqb, wkb, wvb);

    qkv_gemm_async<<<dim3(256, 3), 256, 0, stream>>>(xqb, xkb, xvb, wqb, wkb, wvb,
                                                     bq, bk, bv, cnt,
                                                     q_ws, k_ws, vt_ws);

    attn_kernel<<<dim3((S_ / QB) * B_ * H_), 512, 0, stream>>>(q_ws, k_ws, vt_ws,
                                                               cnt, (float*)d_out);
}